// Round 7
// baseline (218.920 us; speedup 1.0000x reference)
//
#include <hip/hip_runtime.h>
#include <hip/hip_bf16.h>
#include <math.h>

// Problem constants
#define NB    4
#define LQ    512
#define LKV   8192
#define QDIM  1024
#define KVDIM 512
#define NH    8
#define EPS_LN 1e-5f
#define SMAX  12.0f     // fixed softmax baseline (log2 domain); scores*log2e max ~9

typedef __attribute__((ext_vector_type(8))) short bf16x8;
typedef __attribute__((ext_vector_type(4))) float f32x4;

static __device__ __forceinline__ ushort f2bf(float x) {
    unsigned int u = __builtin_bit_cast(unsigned int, x);
    u += 0x7FFFu + ((u >> 16) & 1u);          // round-to-nearest-even
    return (ushort)(u >> 16);
}

#if __has_builtin(__builtin_amdgcn_cvt_pk_bf16_f32)
static __device__ __forceinline__ unsigned int pk_bf16(float a, float b) {
    auto r = __builtin_amdgcn_cvt_pk_bf16_f32(a, b);
    return __builtin_bit_cast(unsigned int, r);
}
#else
static __device__ __forceinline__ unsigned int pk_bf16(float a, float b) {
    return (unsigned int)f2bf(a) | ((unsigned int)f2bf(b) << 16);
}
#endif

#if __has_builtin(__builtin_amdgcn_exp2f)
#define EXP2F(x) __builtin_amdgcn_exp2f(x)
#else
#define EXP2F(x) exp2f(x)
#endif

// async global->LDS, 16B per lane; LDS dest = wave base + lane*16
static __device__ __forceinline__ void gld_lds16(const ushort* g, ushort* l) {
    __builtin_amdgcn_global_load_lds(
        (const __attribute__((address_space(1))) unsigned int*)g,
        (__attribute__((address_space(3))) unsigned int*)l, 16, 0, 0);
}

// 64x64 transpose tile: dst[n][k] = bf16(src[k][n]), src is [K][256].
static __device__ __forceinline__ void wt_transpose_body(
    const float* __restrict__ src, ushort* __restrict__ dst, int K,
    int kx, int ny, int t, ushort (*Ts)[72])
{
    const int k0 = kx * 64, n0 = ny * 64;
    const int nl = t & 63;
#pragma unroll
    for (int p = 0; p < 16; ++p) {
        const int kl = p * 4 + (t >> 6);
        Ts[nl][kl] = f2bf(src[(size_t)(k0 + kl) * 256 + n0 + nl]);
    }
    __syncthreads();
    const int ck = (t & 7) * 8;
#pragma unroll
    for (int p = 0; p < 2; ++p) {
        const int rn = p * 32 + (t >> 3);
        *(bf16x8*)(dst + (size_t)(n0 + rn) * K + k0 + ck) = *(const bf16x8*)&Ts[rn][ck];
    }
}

// ---------------------------------------------------------------------------
// Phase A: LN STATS ONLY (single pass, var = E[x^2]-mu^2) + weight transposes.
// blocks [0,8192): inputs stats (4 rows/blk, wave per row, K=512)
// blocks [8192,8704): hidden stats (K=1024)
// blocks [8704,8832): Wq/Wk/Wv transposes
// ---------------------------------------------------------------------------
__global__ __launch_bounds__(256) void phaseA_kernel(
    const float* __restrict__ inputs, float* __restrict__ mean_i, float* __restrict__ rstd_i,
    const float* __restrict__ hidden, float* __restrict__ mean_h, float* __restrict__ rstd_h,
    const float* __restrict__ Wq, const float* __restrict__ Wk, const float* __restrict__ Wv,
    ushort* __restrict__ WtQ, ushort* __restrict__ WtKV)
{
    __shared__ ushort Ts[64][72];
    const int bid = blockIdx.x;
    const int t = threadIdx.x;
    const int lane = t & 63;
    if (bid < 8192) {
        const int row = bid * 4 + (t >> 6);
        const float* xp = inputs + (size_t)row * KVDIM;
        float s = 0.f, ss = 0.f;
#pragma unroll
        for (int i = 0; i < 2; ++i) {
            const float4 v = *(const float4*)(xp + lane * 4 + i * 256);
            s  += (v.x + v.y) + (v.z + v.w);
            ss += (v.x * v.x + v.y * v.y) + (v.z * v.z + v.w * v.w);
        }
#pragma unroll
        for (int o = 1; o < 64; o <<= 1) { s += __shfl_xor(s, o, 64); ss += __shfl_xor(ss, o, 64); }
        if (lane == 0) {
            const float mu = s * (1.0f / KVDIM);
            mean_i[row] = mu;
            rstd_i[row] = rsqrtf(ss * (1.0f / KVDIM) - mu * mu + EPS_LN);
        }
    } else if (bid < 8704) {
        const int row = (bid - 8192) * 4 + (t >> 6);
        const float* xp = hidden + (size_t)row * QDIM;
        float s = 0.f, ss = 0.f;
#pragma unroll
        for (int i = 0; i < 4; ++i) {
            const float4 v = *(const float4*)(xp + lane * 4 + i * 256);
            s  += (v.x + v.y) + (v.z + v.w);
            ss += (v.x * v.x + v.y * v.y) + (v.z * v.z + v.w * v.w);
        }
#pragma unroll
        for (int o = 1; o < 64; o <<= 1) { s += __shfl_xor(s, o, 64); ss += __shfl_xor(ss, o, 64); }
        if (lane == 0) {
            const float mu = s * (1.0f / QDIM);
            mean_h[row] = mu;
            rstd_h[row] = rsqrtf(ss * (1.0f / QDIM) - mu * mu + EPS_LN);
        }
    } else if (bid < 8768) {
        const int p = bid - 8704;
        wt_transpose_body(Wq, WtQ, QDIM, p & 15, p >> 4, t, Ts);
    } else if (bid < 8800) {
        const int p = bid - 8768;
        wt_transpose_body(Wk, WtKV, KVDIM, p & 7, p >> 3, t, Ts);
    } else {
        const int p = bid - 8800;
        wt_transpose_body(Wv, WtKV + (size_t)256 * KVDIM, KVDIM, p & 7, p >> 3, t, Ts);
    }
}

// ---------------------------------------------------------------------------
// Phase B (one launch, 256 thr):
// blocks [0,1024): KV GEMM 128x128, BK=32, LN fused into A staging (fp32 in),
//   XCD-swizzled so the 4 n-blocks of one m-tile share an XCD (A L2 reuse).
// blocks [1024,1280): Q GEMM 32x64 tiles (256 blocks, full GPU), LN fused.
// ---------------------------------------------------------------------------
__global__ __launch_bounds__(256) void phaseB_kernel(
    const float* __restrict__ inputs,
    const float* __restrict__ mean_i, const float* __restrict__ rstd_i,
    const float* __restrict__ ln2g, const float* __restrict__ ln2b,
    const ushort* __restrict__ WtKV,
    const float* __restrict__ bk, const float* __restrict__ bv,
    ushort* __restrict__ kb, ushort* __restrict__ vt,
    const float* __restrict__ hidden,
    const float* __restrict__ mean_h, const float* __restrict__ rstd_h,
    const float* __restrict__ ln1g, const float* __restrict__ ln1b,
    const ushort* __restrict__ WtQ, const float* __restrict__ bq,
    ushort* __restrict__ qb, float oscale)
{
    __shared__ __align__(16) ushort SMEM[4 * 64 * 72];   // 36864 B
    const int bid  = blockIdx.x;
    const int t    = threadIdx.x;
    const int lane = t & 63;
    const int w    = t >> 6;
    const int lq   = lane & 15;
    const int lg   = lane >> 4;
    const int wm   = w >> 1;
    const int wn   = w & 1;

    if (bid < 1024) {
        // ================= KV GEMM (LN fused) =================
        // XCD swizzle: per XCD 32 m-tiles x 4 n-tiles
        const int x  = bid & 7;
        const int j  = bid >> 3;            // 0..127
        const int bm = (x * 32 + (j >> 2)) * 128;
        const int bn = (j & 3) * 128;
        ushort* As = SMEM;
        ushort* Bs = SMEM + 4096;

        const int srow = t >> 2;                              // 0..63
        const int scol = ((t & 3) ^ ((t >> 3) & 3)) * 8;      // xor-swizzled col
        const ushort* gB = WtKV + (size_t)(bn + srow) * KVDIM + scol;
        ushort* lB  = Bs + t * 8;
        ushort* lA0 = As + t * 8;
        ushort* lA1 = As + 2048 + t * 8;

        const int r0 = bm + srow;
        const float rs0 = rstd_i[r0],      mr0 = -mean_i[r0] * rs0;
        const float rs1 = rstd_i[r0 + 64], mr1 = -mean_i[r0 + 64] * rs1;
        const float* xp0 = inputs + (size_t)r0 * KVDIM + scol;
        const float* xp1 = xp0 + (size_t)64 * KVDIM;

        // preload iter-0 A + LN params
        float4 a0 = *(const float4*)(xp0);
        float4 a1 = *(const float4*)(xp0 + 4);
        float4 c0 = *(const float4*)(xp1);
        float4 c1 = *(const float4*)(xp1 + 4);
        float4 g0 = *(const float4*)(ln2g + scol);
        float4 g1 = *(const float4*)(ln2g + scol + 4);
        float4 e0 = *(const float4*)(ln2b + scol);
        float4 e1 = *(const float4*)(ln2b + scol + 4);

        f32x4 acc[4][4] = {};
        for (int k0 = 0; k0 < KVDIM; k0 += 32) {
            gld_lds16(gB + k0,                       lB);
            gld_lds16(gB + (size_t)64 * KVDIM + k0,  lB + 2048);
            // stage current A (LN -> bf16), layout identical to gld_lds order
            uint4 w0, w1;
            w0.x = pk_bf16(fmaf(fmaf(a0.x, rs0, mr0), g0.x, e0.x), fmaf(fmaf(a0.y, rs0, mr0), g0.y, e0.y));
            w0.y = pk_bf16(fmaf(fmaf(a0.z, rs0, mr0), g0.z, e0.z), fmaf(fmaf(a0.w, rs0, mr0), g0.w, e0.w));
            w0.z = pk_bf16(fmaf(fmaf(a1.x, rs0, mr0), g1.x, e1.x), fmaf(fmaf(a1.y, rs0, mr0), g1.y, e1.y));
            w0.w = pk_bf16(fmaf(fmaf(a1.z, rs0, mr0), g1.z, e1.z), fmaf(fmaf(a1.w, rs0, mr0), g1.w, e1.w));
            w1.x = pk_bf16(fmaf(fmaf(c0.x, rs1, mr1), g0.x, e0.x), fmaf(fmaf(c0.y, rs1, mr1), g0.y, e0.y));
            w1.y = pk_bf16(fmaf(fmaf(c0.z, rs1, mr1), g0.z, e0.z), fmaf(fmaf(c0.w, rs1, mr1), g0.w, e0.w));
            w1.z = pk_bf16(fmaf(fmaf(c1.x, rs1, mr1), g1.x, e1.x), fmaf(fmaf(c1.y, rs1, mr1), g1.y, e1.y));
            w1.w = pk_bf16(fmaf(fmaf(c1.z, rs1, mr1), g1.z, e1.z), fmaf(fmaf(c1.w, rs1, mr1), g1.w, e1.w));
            *(uint4*)lA0 = w0;
            *(uint4*)lA1 = w1;
            // prefetch next iter A + LN params (clamped re-read on last)
            const int nk = (k0 + 32 < KVDIM) ? k0 + 32 : 0;
            a0 = *(const float4*)(xp0 + nk);
            a1 = *(const float4*)(xp0 + nk + 4);
            c0 = *(const float4*)(xp1 + nk);
            c1 = *(const float4*)(xp1 + nk + 4);
            g0 = *(const float4*)(ln2g + nk + scol);
            g1 = *(const float4*)(ln2g + nk + scol + 4);
            e0 = *(const float4*)(ln2b + nk + scol);
            e1 = *(const float4*)(ln2b + nk + scol + 4);
            __syncthreads();
            bf16x8 af[4], bf[4];
#pragma unroll
            for (int mt = 0; mt < 4; ++mt) {
                const int m = wm * 64 + mt * 16 + lq;
                af[mt] = *(const bf16x8*)(As + m * 32 + ((lg ^ ((m >> 1) & 3)) << 3));
            }
#pragma unroll
            for (int nt = 0; nt < 4; ++nt) {
                const int n = wn * 64 + nt * 16 + lq;
                bf[nt] = *(const bf16x8*)(Bs + n * 32 + ((lg ^ ((n >> 1) & 3)) << 3));
            }
#pragma unroll
            for (int mt = 0; mt < 4; ++mt)
#pragma unroll
                for (int nt = 0; nt < 4; ++nt)
                    acc[mt][nt] = __builtin_amdgcn_mfma_f32_16x16x32_bf16(af[mt], bf[nt], acc[mt][nt], 0, 0, 0);
            __syncthreads();
        }

        const int m0base = bm + wm * 64;
        const int bidx   = m0base >> 13;
        const int tokb   = m0base & 8191;

        if (bn < 256) {
            // ---- K path: LDS transpose -> 16B row stores ----
            ushort (*Cs)[72] = (ushort(*)[72])(SMEM + w * 64 * 72);
#pragma unroll
            for (int nt = 0; nt < 4; ++nt) {
                const int n_l = nt * 16 + lq;
                const float bias = bk[bn + wn * 64 + n_l];
#pragma unroll
                for (int mt = 0; mt < 4; ++mt)
#pragma unroll
                    for (int r = 0; r < 4; ++r)
                        Cs[mt * 16 + lg * 4 + r][n_l] = f2bf(acc[mt][nt][r] + bias);
            }
            const int r0_ = lane >> 3;
            const int ck  = (lane & 7) * 8;
            const int nc  = bn + wn * 64 + ck;
            const int h = nc >> 5, d = nc & 31;
            const size_t obase = (((size_t)(bidx * NH + h) << 13) + tokb) * 32 + d;
#pragma unroll
            for (int p = 0; p < 8; ++p) {
                const int row = p * 8 + r0_;
                *(bf16x8*)(kb + obase + (size_t)row * 32) = *(const bf16x8*)&Cs[row][ck];
            }
        } else {
            // ---- V path: vT[bh][d][tok] via per-wave LDS transpose ----
            ushort (*Cs)[72] = (ushort(*)[72])(SMEM + w * 64 * 72);
#pragma unroll
            for (int nt = 0; nt < 4; ++nt) {
                const int n_l = nt * 16 + lq;
                const float bias = bv[(bn - 256) + wn * 64 + n_l];
#pragma unroll
                for (int mt = 0; mt < 4; ++mt) {
                    uint2 o;
                    o.x = pk_bf16(acc[mt][nt][0] + bias, acc[mt][nt][1] + bias);
                    o.y = pk_bf16(acc[mt][nt][2] + bias, acc[mt][nt][3] + bias);
                    *(uint2*)&Cs[n_l][mt * 16 + lg * 4] = o;
                }
            }
            const int r0_ = lane >> 3;
            const int cm  = (lane & 7) * 8;
            const int tokc = tokb + cm;
#pragma unroll
            for (int p = 0; p < 8; ++p) {
                const int row = p * 8 + r0_;
                const int nv  = (bn - 256) + wn * 64 + row;
                const int h = nv >> 5, d = nv & 31;
                *(bf16x8*)(vt + ((size_t)(bidx * NH + h) * 32 + d) * LKV + tokc) =
                    *(const bf16x8*)&Cs[row][cm];
            }
        }
    } else {
        // ================= Q GEMM (32x64 tile, LN fused) =================
        const int p  = bid - 1024;          // 0..255
        const int x  = p & 7;
        const int j  = p >> 3;              // 0..31
        const int bm = (x * 8 + (j >> 2)) * 32;
        const int bn = (j & 3) * 64;
        ushort* As = SMEM;                  // 32 x 64
        ushort* Bs = SMEM + 2048;           // 64 x 64

        const int srow = t >> 3;                              // 0..31
        const int scol = ((t & 7) ^ (srow & 7)) * 8;          // xor-swizzled col
        const ushort* gB = WtQ + (size_t)(bn + srow) * QDIM + scol;
        ushort* lB = Bs + t * 8;
        ushort* lA = As + t * 8;

        const int r = bm + srow;
        const float rs0 = rstd_h[r], mr0 = -mean_h[r] * rs0;
        const float* xA = hidden + (size_t)r * QDIM + scol;

        float4 a0 = *(const float4*)(xA);
        float4 a1 = *(const float4*)(xA + 4);
        float4 g0 = *(const float4*)(ln1g + scol);
        float4 g1 = *(const float4*)(ln1g + scol + 4);
        float4 e0 = *(const float4*)(ln1b + scol);
        float4 e1 = *(const float4*)(ln1b + scol + 4);

        f32x4 acc[2] = {};
        for (int k0 = 0; k0 < QDIM; k0 += 64) {
            gld_lds16(gB + k0,                      lB);
            gld_lds16(gB + (size_t)32 * QDIM + k0,  lB + 2048);
            uint4 w0;
            w0.x = pk_bf16(fmaf(fmaf(a0.x, rs0, mr0), g0.x, e0.x), fmaf(fmaf(a0.y, rs0, mr0), g0.y, e0.y));
            w0.y = pk_bf16(fmaf(fmaf(a0.z, rs0, mr0), g0.z, e0.z), fmaf(fmaf(a0.w, rs0, mr0), g0.w, e0.w));
            w0.z = pk_bf16(fmaf(fmaf(a1.x, rs0, mr0), g1.x, e1.x), fmaf(fmaf(a1.y, rs0, mr0), g1.y, e1.y));
            w0.w = pk_bf16(fmaf(fmaf(a1.z, rs0, mr0), g1.z, e1.z), fmaf(fmaf(a1.w, rs0, mr0), g1.w, e1.w));
            *(uint4*)lA = w0;
            const int nk = (k0 + 64 < QDIM) ? k0 + 64 : 0;
            a0 = *(const float4*)(xA + nk);
            a1 = *(const float4*)(xA + nk + 4);
            g0 = *(const float4*)(ln1g + nk + scol);
            g1 = *(const float4*)(ln1g + nk + scol + 4);
            e0 = *(const float4*)(ln1b + nk + scol);
            e1 = *(const float4*)(ln1b + nk + scol + 4);
            __syncthreads();
#pragma unroll
            for (int kh = 0; kh < 2; ++kh) {
                const int m = wm * 16 + lq;
                const bf16x8 af = *(const bf16x8*)(As + m * 64 + (((lg + 4 * kh) ^ (m & 7)) << 3));
#pragma unroll
                for (int nt = 0; nt < 2; ++nt) {
                    const int n = wn * 32 + nt * 16 + lq;
                    const bf16x8 bf = *(const bf16x8*)(Bs + n * 64 + (((lg + 4 * kh) ^ (n & 7)) << 3));
                    acc[nt] = __builtin_amdgcn_mfma_f32_16x16x32_bf16(af, bf, acc[nt], 0, 0, 0);
                }
            }
            __syncthreads();
        }

#pragma unroll
        for (int nt = 0; nt < 2; ++nt) {
            const int n = bn + wn * 32 + nt * 16 + lq;
            const int h = n >> 5, d = n & 31;
            const float bias = bq[n];
            const int m0   = bm + wm * 16 + lg * 4;
            const int bidx = m0 >> 9;
            const int tok  = m0 & 511;
            const size_t base = (((size_t)(bidx * NH + h) << 9) + tok) * 32 + d;
#pragma unroll
            for (int rr_ = 0; rr_ < 4; ++rr_)
                qb[base + (size_t)rr_ * 32] = f2bf((acc[nt][rr_] + bias) * oscale);
        }
    }
}

// ---------------------------------------------------------------------------
// MFMA flash attention, fixed-baseline softmax, q-tile 32, 32-KV iterations,
// DEFERRED PV: iteration i computes QK_i/exp_i/write_i and PV_{i-1} from the
// other LDS buffer — no same-iteration LDS RAW wait on the critical path.
// Grid 512 (XCD-swizzled), 512 thr = 8 waves; wave w owns KV [w*1024,+1024).
// ---------------------------------------------------------------------------
__global__ __launch_bounds__(512, 4) void attn_mfma_kernel(
    const ushort* __restrict__ Qb,  // [B*H][LQ][32] bf16, pre-scaled by log2e/sqrt(32)
    const ushort* __restrict__ Kb,  // [B*H][LKV][32]
    const ushort* __restrict__ Vt,  // [B*H][32][LKV]
    float* __restrict__ Out)        // [B][LQ][256]
{
    const int bid = blockIdx.x;
    const int xcd = bid & 7;
    const int rr  = bid >> 3;
    const int bh  = ((rr & 3) << 3) | xcd;   // 4 bh per XCD -> K/V L2-resident
    const int qt  = rr >> 2;                 // 0..15 (q-tile of 32)
    const int b = bh >> 3, h = bh & 7;
    const int t = threadIdx.x, w = t >> 6, lane = t & 63;
    const int lq = lane & 15, lg = lane >> 4;

    __shared__ __align__(16) ushort Pb[2][8][32][40];   // 40960 B; aliased as Ob f32 post-loop
    __shared__ float lbuf[8][32];

    bf16x8 qfrag[2];
    const size_t qbase = ((size_t)bh * LQ + qt * 32) * 32;
    qfrag[0] = *(const bf16x8*)(Qb + qbase + (size_t)lq * 32 + lg * 8);
    qfrag[1] = *(const bf16x8*)(Qb + qbase + (size_t)(16 + lq) * 32 + lg * 8);

    const ushort* KpA = Kb + ((size_t)bh * LKV + w * 1024 + lq) * 32 + lg * 8;
    const ushort* VpA = Vt + ((size_t)bh * 32 + lq) * LKV + w * 1024 + lg * 8;

    f32x4 oacc[2][2] = {};        // [d-tile][q-tile]
    float l_part[2] = {0.f, 0.f};
    const f32x4 cM = {-SMAX, -SMAX, -SMAX, -SMAX};

    ushort* P0 = &Pb[0][w][0][0];
    ushort* P1 = &Pb[1][w][0][0];

    bf16x8 kf0 = *(const bf16x8*)(KpA);
    bf16x8 kf1 = *(const bf16x8*)(KpA + 16 * 32);
    bf16x8 vf0 = *(const bf16x8*)(VpA);
    bf16x8 vf1 = *(const bf16x8*)(VpA + (size_t)16 * LKV);

    bf16x8 vp0, vp1;   // V frags matching the pending (previous) P

#define ATTN_EXPW(Pdst, s00, s10, s01, s11)                                              \
    do {                                                                                 \
        float p0, p1, p2, p3; uint2 pw;                                                  \
        p0 = EXP2F((s00)[0]); p1 = EXP2F((s00)[1]); p2 = EXP2F((s00)[2]); p3 = EXP2F((s00)[3]); \
        l_part[0] += (p0 + p1) + (p2 + p3);                                              \
        pw.x = pk_bf16(p0, p1); pw.y = pk_bf16(p2, p3);                                  \
        *(uint2*)((Pdst) + (lq) * 40 + lg * 4) = pw;                                     \
        p0 = EXP2F((s10)[0]); p1 = EXP2F((s10)[1]); p2 = EXP2F((s10)[2]); p3 = EXP2F((s10)[3]); \
        l_part[0] += (p0 + p1) + (p2 + p3);                                              \
        pw.x = pk_bf16(p0, p1); pw.y = pk_bf16(p2, p3);                                  \
        *(uint2*)((Pdst) + (lq) * 40 + 16 + lg * 4) = pw;                                \
        p0 = EXP2F((s01)[0]); p1 = EXP2F((s01)[1]); p2 = EXP2F((s01)[2]); p3 = EXP2F((s01)[3]); \
        l_part[1] += (p0 + p1) + (p2 + p3);                                              \
        pw.x = pk_bf16(p0, p1); pw.y = pk_bf16(p2, p3);                                  \
        *(uint2*)((Pdst) + (16 + lq) * 40 + lg * 4) = pw;                                \
        p0 = EXP2F((s11)[0]); p1 = EXP2F((s11)[1]); p2 = EXP2F((s11)[2]); p3 = EXP2F((s11)[3]); \
        l_part[1] += (p0 + p1) + (p2 + p3);                                              \
        pw.x = pk_bf16(p0, p1); pw.y = pk_bf16(p2, p3);                                  \
        *(uint2*)((Pdst) + (16 + lq) * 40 + 16 + lg * 4) = pw;                           \
    } while (0)

    // ---- iteration 0 (peeled): QK/exp/write P0, no PV yet ----
    {
        const bf16x8 kc0 = kf0, kc1 = kf1;
        vp0 = vf0; vp1 = vf1;
        kf0 = *(const bf16x8*)(KpA + (size_t)32 * 32);
        kf1 = *(const bf16x8*)(KpA + (size_t)48 * 32);
        vf0 = *(const bf16x8*)(VpA + 32);
        vf1 = *(const bf16x8*)(VpA + (size_t)16 * LKV + 32);
        f32x4 s00 = __builtin_amdgcn_mfma_f32_16x16x32_bf16(kc0, qfrag[0], cM, 0, 0, 0);
        f32x4 s01 = __builtin_amdgcn_mfma_f32_16x16x32_bf16(kc0, qfrag[1], cM, 0, 0, 0);
        f32x4 s10 = __builtin_amdgcn_mfma_f32_16x16x32_bf16(kc1, qfrag[0], cM, 0, 0, 0);
        f32x4 s11 = __builtin_amdgcn_mfma_f32_16x16x32_bf16(kc1, qfrag[1], cM, 0, 0, 0);
        ATTN_EXPW(P0, s00, s10, s01, s11);
    }

    for (int kt = 32; kt < 1024; kt += 32) {
        ushort* Pw = (kt & 32) ? P1 : P0;    // buffer for iter i = kt/32
        ushort* Pr = (kt & 32) ? P0 : P1;    // previous iter's buffer
        const bf16x8 kc0 = kf0, kc1 = kf1, vc0 = vf0, vc1 = vf1;
        const int nk = (kt + 32 < 1024) ? kt + 32 : 0;   // clamp: harmless re-read
        kf0 = *(const bf16x8*)(KpA + (size_t)nk * 32);
        kf1 = *(const bf16x8*)(KpA + (size_t)(nk + 16) * 32);
        vf0 = *(const bf16x8*)(VpA + nk);
        vf1 = *(const bf16x8*)(VpA + (size_t)16 * LKV + nk);

        // QK for iter i
        f32x4 s00 = __builtin_amdgcn_mfma_f32_16x16x32_bf16(kc0, qfrag[0], cM, 0, 0, 0);
        f32x4 s01 = __builtin_amdgcn_mfma_f32_16x16x32_bf16(kc0, qfrag[1], cM, 0, 0, 0);
        f32x4 s10 = __builtin_amdgcn_mfma_f32_16x16x32_bf16(kc1, qfrag[0], cM, 0, 0, 0);
        f32x4 s11 = __builtin_amdgcn_mfma_f32_16x16x32_bf16(kc1, qfrag[1], cM, 0, 0, 0);

        // PV for iter i-1 (other buffer, no RAW wait on this iter's writes)
        const bf16x8 pf0 = *(const bf16x8*)(Pr + (size_t)lq * 40 + lg * 8);
        const bf16x8 pf1 = *(const bf16x8*)(Pr + (size_t)(16 + lq) * 40 + lg * 8);
        oacc[0][0] = __builtin_amdgcn_mfma_f32_16x16x32_bf16(vp0, pf0, oacc[0][0], 0, 0, 0);
        oacc[0][1] = __builtin_amdgcn_mfma_f32_16x16x32_bf16(vp0, pf1, oacc[0][1], 0, 0, 0);
        oacc[1][0] = __builtin_amdgcn_mfma_f32_16x16x32_bf16(vp1, pf0, oacc[1][0], 0, 0, 0);
        oacc[1][1] = __builtin_amdgcn_mfma_f32_16x16x32_bf16(vp1, pf1, oacc[1][1], 0, 0, 0);
        vp0 = vc0; vp1 = vc1;

        ATTN_EXPW(Pw, s00, s10, s01, s11);
    }

    // ---- tail PV: last iter (kt=992 -> buffer P1) ----
    {
        const bf16x8 pf0 = *(const bf16x8*)(P1 + (size_t)lq * 40 + lg * 8);
        const bf16x8 pf1 = *(const bf16x8*)(P1 + (size_t)(16 + lq) * 40 + lg * 8);
        oacc[0][0] = __builtin_amdgcn_mfma_f32_16x16x32_bf16(vp0, pf0, oacc[0][0], 0, 0, 0);
        oacc[0][1] = __builtin_amdgcn_mfma_f32_16x16x32_bf16(vp0, pf1, oacc[0][1], 0, 0, 0);
        oacc[1][0] = __builtin_amdgcn_mfma_f32_16x16x32_bf16(vp1, pf0, oacc[1][0], 0, 0, 0);
        oacc[1][1] = __builtin_amdgcn_mfma_f32_16x16x32_bf16(vp1, pf1, oacc[1][1], 0, 0, 0);
    }
#undef ATTN_EXPW

    // ---- l reduce + 8-wave combine ----
#pragma unroll
    for (int n = 0; n < 2; ++n) {
        l_part[n] += __shfl_xor(l_part[n], 16);
        l_part[n] += __shfl_xor(l_part[n], 32);
    }
    if (lg == 0) {
        lbuf[w][lq]      = l_part[0];
        lbuf[w][16 + lq] = l_part[1];
    }
    __syncthreads();   // all waves done with P LDS; lbuf visible

    float* Ob = (float*)&Pb[0][0][0][0];   // [4][32][36] f32 scratch, aliases Pb
    if (w >= 4) {
#pragma unroll
        for (int n = 0; n < 2; ++n)
#pragma unroll
            for (int dt = 0; dt < 2; ++dt)
                *(f32x4*)&Ob[((size_t)(w - 4) * 32 + n * 16 + lq) * 36 + dt * 16 + lg * 4] = oacc[dt][n];
    }
    __syncthreads();
    if (w < 4) {
#pragma unroll
        for (int n = 0; n < 2; ++n)
#pragma unroll
            for (int dt = 0; dt < 2; ++dt) {
                float* p = &Ob[((size_t)w * 32 + n * 16 + lq) * 36 + dt * 16 + lg * 4];
                f32x4 v = *(f32x4*)p;
                v += oacc[dt][n];
                *(f32x4*)p = v;
            }
    }
    __syncthreads();
    {
        const int q  = t >> 4;           // 0..31
        const int d0 = (t & 15) * 2;     // 0..30
        float s0 = 0.f, s1 = 0.f;
#pragma unroll
        for (int j = 0; j < 4; ++j) {
            s0 += Ob[((size_t)j * 32 + q) * 36 + d0];
            s1 += Ob[((size_t)j * 32 + q) * 36 + d0 + 1];
        }
        float gl = 0.f;
#pragma unroll
        for (int j = 0; j < 8; ++j) gl += lbuf[j][q];
        const float inv = 1.0f / gl;
        float2 o; o.x = s0 * inv; o.y = s1 * inv;
        *(float2*)(Out + ((size_t)b * LQ + qt * 32 + q) * 256 + h * 32 + d0) = o;
    }
}

// ---------------------------------------------------------------------------
extern "C" void kernel_launch(void* const* d_in, const int* in_sizes, int n_in,
                              void* d_out, int out_size, void* d_ws, size_t ws_size,
                              hipStream_t stream)
{
    const float* hidden = (const float*)d_in[0];
    const float* inputs = (const float*)d_in[1];
    const float* ln1g   = (const float*)d_in[2];
    const float* ln1b   = (const float*)d_in[3];
    const float* ln2g   = (const float*)d_in[4];
    const float* ln2b   = (const float*)d_in[5];
    const float* Wq     = (const float*)d_in[6];
    const float* bq     = (const float*)d_in[7];
    const float* Wk     = (const float*)d_in[8];
    const float* bk     = (const float*)d_in[9];
    const float* Wv     = (const float*)d_in[10];
    const float* bv     = (const float*)d_in[11];
    float* out = (float*)d_out;

    // workspace (bytes), total ~34.5 MB
    char* wsb = (char*)d_ws;
    ushort* qb     = (ushort*)(wsb);                               // 1 MB    [32][512][32]
    ushort* WtKV   = (ushort*)(wsb + (1u << 20));                  // 0.5 MB  [512][512]
    ushort* WtQ    = (ushort*)(wsb + (1u << 20) + (512u << 10));   // 0.5 MB  [256][1024]
    float*  mean_i = (float*)(wsb + (2u << 20));                   // 128 KB
    float*  rstd_i = (float*)(wsb + (2u << 20) + (128u << 10));    // 128 KB
    float*  mean_h = (float*)(wsb + (2u << 20) + (256u << 10));    // 8 KB
    float*  rstd_h = (float*)(wsb + (2u << 20) + (264u << 10));    // 8 KB
    ushort* kb     = (ushort*)(wsb + (2u << 20) + (512u << 10));   // 16 MB   [32][8192][32]
    ushort* vt     = (ushort*)(wsb + (18u << 20) + (512u << 10));  // 16 MB   [32][32][8192]

    const float oscale = 0.2550540226496112f;   // log2(e)/sqrt(32): log2-domain softmax

    phaseA_kernel<<<8832, 256, 0, stream>>>(inputs, mean_i, rstd_i,
                                            hidden, mean_h, rstd_h,
                                            Wq, Wk, Wv, WtQ, WtKV);
    phaseB_kernel<<<1280, 256, 0, stream>>>(inputs, mean_i, rstd_i, ln2g, ln2b,
                                            WtKV, bk, bv, kb, vt,
                                            hidden, mean_h, rstd_h, ln1g, ln1b,
                                            WtQ, bq, qb, oscale);
    attn_mfma_kernel<<<512, 512, 0, stream>>>(qb, kb, vt, out);
}